// Round 7
// baseline (143.045 us; speedup 1.0000x reference)
//
#include <hip/hip_runtime.h>
#include <hip/hip_bf16.h>

#define H_    32
#define HKV_  8
#define D_    128
#define HID_  4096
#define NQKV  6144            // 4096 + 1024 + 1024
#define SPLIT 128             // split-K for the GEMVs (rows per chunk = 32)
#define CHUNK 256             // tokens per attention block
#define NIT   (CHUNK / 8)     // 32 iterations, 8 tokens each
#define S_    32768
#define NCHUNK (S_ / CHUNK)   // 128
#define SCALE_ 0.08838834764831843f  // 1/sqrt(128)
#define BASE_  8.0f           // fixed softmax base: wgt = exp(s - 8), exact (cancels)

// DPP cross-lane adds (VALU-only, no DS pipe, no lgkmcnt drains)
// quad_perm xor1 = [1,0,3,2] = 0xB1 ; xor2 = [2,3,0,1] = 0x4E ; row_ror:8 = 0x128 (l^8 within 16)
#define DPP_ADD(v, ctrl) ((v) + __int_as_float(__builtin_amdgcn_update_dpp( \
    0, __float_as_int(v), (ctrl), 0xF, 0xF, true)))

// workspace layout (float offsets)
#define WS_QKV_PART 0                       // [SPLIT][NQKV]          786432
#define WS_QKV      786432                  // [NQKV]                 6144
#define WS_PV_C     792576                  // [NCHUNK][HKV][4][D]    524288
#define WS_L_C      1316864                 // [NCHUNK][HKV][4]       4096
#define WS_ATTN     1320960                 // [H*D]                  4096
#define WS_OPART    1325056                 // [SPLIT][HID]           524288
// total ~1.85M floats = ~7.4 MB

// ---------------- kernel 1: QKV GEMV split-K partials ----------------
__global__ __launch_bounds__(256) void k_qkv_part(
    const float* __restrict__ hid, const float* __restrict__ Wq,
    const float* __restrict__ Wk, const float* __restrict__ Wv,
    float* __restrict__ part)
{
    const int j0 = blockIdx.x * 1024 + threadIdx.x * 4;   // 6 col-blocks of 1024
    const int i0 = blockIdx.y * (HID_ / SPLIT);           // 32-row chunk
    __shared__ float hs[HID_ / SPLIT];
    if (threadIdx.x < HID_ / SPLIT) hs[threadIdx.x] = hid[i0 + threadIdx.x];
    __syncthreads();

    const float* W; int ldw; int col;
    if (j0 < 4096)       { W = Wq; ldw = 4096; col = j0; }
    else if (j0 < 5120)  { W = Wk; ldw = 1024; col = j0 - 4096; }
    else                 { W = Wv; ldw = 1024; col = j0 - 5120; }

    float4 acc = {0.f, 0.f, 0.f, 0.f};
    const float* p = W + (size_t)i0 * ldw + col;
    #pragma unroll 8
    for (int i = 0; i < HID_ / SPLIT; ++i) {
        const float4 wv = *(const float4*)(p + (size_t)i * ldw);
        const float h = hs[i];
        acc.x += h * wv.x; acc.y += h * wv.y; acc.z += h * wv.z; acc.w += h * wv.w;
    }
    *(float4*)&part[(size_t)blockIdx.y * NQKV + j0] = acc;
}

// ---------------- kernel 2: reduce partials + RoPE ----------------
__global__ __launch_bounds__(256) void k_qkv_reduce(
    const float* __restrict__ part, const float* __restrict__ cosv,
    const float* __restrict__ sinv, float* __restrict__ qkv)
{
    const int j = blockIdx.x * 256 + threadIdx.x;  // 24 blocks
    float s = 0.f;
    #pragma unroll 8
    for (int k = 0; k < SPLIT; ++k) s += part[(size_t)k * NQKV + j];
    __shared__ float buf[256];
    buf[threadIdx.x] = s;
    __syncthreads();
    float out = s;
    if (j < 5120) {  // q and k get RoPE; v passes through
        const int d = j & 127;
        const float rot = (d < 64) ? -buf[threadIdx.x + 64] : buf[threadIdx.x - 64];
        out = s * cosv[d] + rot * sinv[d];
    }
    qkv[j] = out;
}

// ---------------- kernel 3: fused flash-decode attention ----------------
// block = 256 thr = 4 waves; wave g handles head (kh*4+g); waves independent
// (no LDS, no barriers) — the 4 waves read the same K/V rows ~in lockstep, so
// L1 serves 3 of the 4 (verified: FETCH_SIZE ~ 1x not 4x in R5).
// Lane mapping: d-slice j = lane bits {0,1,3}, token slot t = bits {2,4,5}.
// j-reduction = quad_perm(xor1) + quad_perm(xor2) + row_ror:8 — all DPP, no
// DS-pipe ops in the hot loop. dot uses 4 split accumulators (short dep chain).
// Explicit 2-deep register prefetch: iteration i+1's loads issue before
// iteration i's compute. Fixed-base softmax wgt = exp(s-8) (exact, cancels).
__global__ __launch_bounds__(256) void k_attn(
    const int* __restrict__ kqx, const float* __restrict__ kscale,
    const int* __restrict__ vqx, const float* __restrict__ vscale,
    const float* __restrict__ qkv, float* __restrict__ pv_c,
    float* __restrict__ l_c)
{
    const int kh = blockIdx.y;
    const int c0 = blockIdx.x * CHUNK;
    const int tid = threadIdx.x;
    const int g = tid >> 6;                       // wave = head-in-group
    const int l = tid & 63;
    const int j = (l & 3) | ((l >> 1) & 4);       // d-slice: bits 0,1,3
    const int t = ((l >> 2) & 1) | ((l >> 3) & 6);// token slot: bits 2,4,5

    float4 qf[4];
    #pragma unroll
    for (int k = 0; k < 4; ++k)
        qf[k] = *(const float4*)&qkv[(kh * 4 + g) * D_ + (j + 8 * k) * 4];

    float ls = 0.f;
    float4 acc[4];
    #pragma unroll
    for (int k = 0; k < 4; ++k) acc[k] = make_float4(0.f, 0.f, 0.f, 0.f);

    // --- prefetch registers (cur / nxt) ---
    int4 kc[4], vc[4], kn[4], vn[4];
    float scc, vsc, scn, vsn;

    {   // prologue: load iteration 0
        const int tok = c0 + t;
        const size_t row = ((size_t)tok * HKV_ + kh) * D_;
        #pragma unroll
        for (int k = 0; k < 4; ++k) {
            kc[k] = *(const int4*)(kqx + row + (j + 8 * k) * 4);
            vc[k] = *(const int4*)(vqx + row + (j + 8 * k) * 4);
        }
        scc = kscale[(size_t)tok * HKV_ + kh];
        vsc = vscale[(size_t)tok * HKV_ + kh];
    }

    #pragma unroll 2
    for (int it = 0; it < NIT; ++it) {
        if (it + 1 < NIT) {   // issue next iteration's loads first
            const int tok = c0 + (it + 1) * 8 + t;
            const size_t row = ((size_t)tok * HKV_ + kh) * D_;
            #pragma unroll
            for (int k = 0; k < 4; ++k) {
                kn[k] = *(const int4*)(kqx + row + (j + 8 * k) * 4);
                vn[k] = *(const int4*)(vqx + row + (j + 8 * k) * 4);
            }
            scn = kscale[(size_t)tok * HKV_ + kh];
            vsn = vscale[(size_t)tok * HKV_ + kh];
        }

        // dot with 4 split accumulators
        float d0 = 0.f, d1 = 0.f, d2 = 0.f, d3 = 0.f;
        d0 += (float)kc[0].x * qf[0].x + (float)kc[0].y * qf[0].y +
              (float)kc[0].z * qf[0].z + (float)kc[0].w * qf[0].w;
        d1 += (float)kc[1].x * qf[1].x + (float)kc[1].y * qf[1].y +
              (float)kc[1].z * qf[1].z + (float)kc[1].w * qf[1].w;
        d2 += (float)kc[2].x * qf[2].x + (float)kc[2].y * qf[2].y +
              (float)kc[2].z * qf[2].z + (float)kc[2].w * qf[2].w;
        d3 += (float)kc[3].x * qf[3].x + (float)kc[3].y * qf[3].y +
              (float)kc[3].z * qf[3].z + (float)kc[3].w * qf[3].w;
        float dot = (d0 + d1) + (d2 + d3);

        // j-reduction, all-DPP (xor1, xor2, xor8 over lane bits 0,1,3)
        dot = DPP_ADD(dot, 0xB1);   // quad_perm [1,0,3,2]
        dot = DPP_ADD(dot, 0x4E);   // quad_perm [2,3,0,1]
        dot = DPP_ADD(dot, 0x128);  // row_ror:8  (l^8 within 16)

        const float wgt = __expf(dot * scc * SCALE_ - BASE_);
        ls += wgt;
        const float wv = wgt * vsc;
        #pragma unroll
        for (int k = 0; k < 4; ++k) {
            acc[k].x += wv * (float)vc[k].x;
            acc[k].y += wv * (float)vc[k].y;
            acc[k].z += wv * (float)vc[k].z;
            acc[k].w += wv * (float)vc[k].w;
        }

        // rotate prefetch regs (renamed away by unroll-2)
        #pragma unroll
        for (int k = 0; k < 4; ++k) { kc[k] = kn[k]; vc[k] = vn[k]; }
        scc = scn; vsc = vsn;
    }

    // epilogue: reduce across token slots t (lane bits 2,4,5)
    #pragma unroll
    for (int kk = 0; kk < 3; ++kk) {
        const int msk = (kk == 0) ? 4 : (kk == 1) ? 16 : 32;
        #pragma unroll
        for (int k = 0; k < 4; ++k) {
            acc[k].x += __shfl_xor(acc[k].x, msk, 64);
            acc[k].y += __shfl_xor(acc[k].y, msk, 64);
            acc[k].z += __shfl_xor(acc[k].z, msk, 64);
            acc[k].w += __shfl_xor(acc[k].w, msk, 64);
        }
        ls += __shfl_xor(ls, msk, 64);
    }
    if (t == 0) {   // lanes {0,1,2,3,8,9,10,11} hold j = 0..7
        float* dst = pv_c + ((size_t)(blockIdx.x * HKV_ + kh) * 4 + g) * D_;
        #pragma unroll
        for (int k = 0; k < 4; ++k) *(float4*)(dst + (j + 8 * k) * 4) = acc[k];
        if (j == 0) l_c[(blockIdx.x * HKV_ + kh) * 4 + g] = ls;
    }
}

// ---------------- kernel 4: combine (pure sums, fixed base) ----------------
// one block per head; 128 threads = d
__global__ __launch_bounds__(128) void k_combine(
    const float* __restrict__ pv_c, const float* __restrict__ l_c,
    const float* __restrict__ qkv, float* __restrict__ attn)
{
    const int h = blockIdx.x;        // 32 blocks
    const int d = threadIdx.x;       // 128
    const int kh = h >> 2, g = h & 3;

    __shared__ float sred[128];
    sred[d] = qkv[h * D_ + d] * qkv[4096 + kh * D_ + d];
    __syncthreads();
    for (int s2 = 64; s2 > 0; s2 >>= 1) {
        if (d < s2) sred[d] += sred[d + s2];
        __syncthreads();
    }
    const float pc = __expf(sred[0] * SCALE_ - BASE_);  // current-token weight

    float pv = 0.f, dsum = 0.f;
    for (int c = 0; c < NCHUNK; ++c) {
        pv   += pv_c[((size_t)(c * HKV_ + kh) * 4 + g) * D_ + d];
        dsum += l_c[(c * HKV_ + kh) * 4 + g];
    }
    const float vcur = qkv[5120 + kh * D_ + d];
    attn[h * D_ + d] = (pv + pc * vcur) / (dsum + pc);
}

// ---------------- kernel 5: output GEMV split-K partials ----------------
__global__ __launch_bounds__(256) void k_out_part(
    const float* __restrict__ attn, const float* __restrict__ Wo,
    float* __restrict__ opart)
{
    const int j0 = blockIdx.x * 1024 + threadIdx.x * 4;  // 4 col-blocks
    const int i0 = blockIdx.y * (HID_ / SPLIT);
    __shared__ float hs[HID_ / SPLIT];
    if (threadIdx.x < HID_ / SPLIT) hs[threadIdx.x] = attn[i0 + threadIdx.x];
    __syncthreads();
    float4 acc = {0.f, 0.f, 0.f, 0.f};
    const float* p = Wo + (size_t)i0 * HID_ + j0;
    #pragma unroll 8
    for (int i = 0; i < HID_ / SPLIT; ++i) {
        const float4 wv = *(const float4*)(p + (size_t)i * HID_);
        const float h = hs[i];
        acc.x += h * wv.x; acc.y += h * wv.y; acc.z += h * wv.z; acc.w += h * wv.w;
    }
    *(float4*)&opart[(size_t)blockIdx.y * HID_ + j0] = acc;
}

// ---------------- kernel 6: reduce output partials ----------------
__global__ __launch_bounds__(256) void k_out_reduce(
    const float* __restrict__ opart, float* __restrict__ out)
{
    const int j = blockIdx.x * 256 + threadIdx.x;  // 16 blocks
    float s = 0.f;
    #pragma unroll 8
    for (int k = 0; k < SPLIT; ++k) s += opart[(size_t)k * HID_ + j];
    out[j] = s;
}

extern "C" void kernel_launch(void* const* d_in, const int* in_sizes, int n_in,
                              void* d_out, int out_size, void* d_ws, size_t ws_size,
                              hipStream_t stream) {
    const float* hid    = (const float*)d_in[0];
    const int*   kqx    = (const int*)d_in[1];
    const float* kscale = (const float*)d_in[2];
    const int*   vqx    = (const int*)d_in[3];
    const float* vscale = (const float*)d_in[4];
    const float* cosv   = (const float*)d_in[5];
    const float* sinv   = (const float*)d_in[6];
    const float* Wq     = (const float*)d_in[7];
    const float* Wk     = (const float*)d_in[8];
    const float* Wv     = (const float*)d_in[9];
    const float* Wo     = (const float*)d_in[10];
    float* ws  = (float*)d_ws;
    float* out = (float*)d_out;

    k_qkv_part  <<<dim3(6, SPLIT), 256, 0, stream>>>(hid, Wq, Wk, Wv, ws + WS_QKV_PART);
    k_qkv_reduce<<<dim3(24),       256, 0, stream>>>(ws + WS_QKV_PART, cosv, sinv, ws + WS_QKV);
    k_attn      <<<dim3(NCHUNK, HKV_), 256, 0, stream>>>(kqx, kscale, vqx, vscale,
                                                         ws + WS_QKV, ws + WS_PV_C,
                                                         ws + WS_L_C);
    k_combine   <<<dim3(H_),       128, 0, stream>>>(ws + WS_PV_C, ws + WS_L_C,
                                                     ws + WS_QKV, ws + WS_ATTN);
    k_out_part  <<<dim3(4, SPLIT), 256, 0, stream>>>(ws + WS_ATTN, Wo, ws + WS_OPART);
    k_out_reduce<<<dim3(16),       256, 0, stream>>>(ws + WS_OPART, out);
}

// Round 8
// 138.426 us; speedup vs baseline: 1.0334x; 1.0334x over previous
//
#include <hip/hip_runtime.h>
#include <hip/hip_bf16.h>

#define H_    32
#define HKV_  8
#define D_    128
#define HID_  4096
#define NQKV  6144            // 4096 + 1024 + 1024
#define SPLIT 128             // split-K for the GEMVs (rows per chunk = 32)
#define CHUNK 256             // tokens per attention block
#define TB    16              // tokens per LDS tile
#define NT    (CHUNK / TB)    // 16 tiles per block
#define S_    32768
#define NCHUNK (S_ / CHUNK)   // 128
#define SCALE_ 0.08838834764831843f  // 1/sqrt(128)
#define BASE_  8.0f           // fixed softmax base: wgt = exp(s - 8), exact (cancels)

// async global->LDS copies (dest = wave-uniform base + lane*size)
#define GLOAD_LDS16(g, l) __builtin_amdgcn_global_load_lds( \
    (const __attribute__((address_space(1))) void*)(g),     \
    (__attribute__((address_space(3))) void*)(l), 16, 0, 0)
#define GLOAD_LDS4(g, l) __builtin_amdgcn_global_load_lds(  \
    (const __attribute__((address_space(1))) void*)(g),     \
    (__attribute__((address_space(3))) void*)(l), 4, 0, 0)
#define WAITV(N) asm volatile("s_waitcnt vmcnt(" #N ")" ::: "memory")

// workspace layout (float offsets)
#define WS_QKV_PART 0                       // [SPLIT][NQKV]          786432
#define WS_QKV      786432                  // [NQKV]                 6144
#define WS_PV_C     792576                  // [NCHUNK][HKV][4][D]    524288
#define WS_L_C      1316864                 // [NCHUNK][HKV][4]       4096
#define WS_ATTN     1320960                 // [H*D]                  4096
#define WS_OPART    1325056                 // [SPLIT][HID]           524288
// total ~1.85M floats = ~7.4 MB

// ---------------- kernel 1: QKV GEMV split-K partials ----------------
__global__ __launch_bounds__(256) void k_qkv_part(
    const float* __restrict__ hid, const float* __restrict__ Wq,
    const float* __restrict__ Wk, const float* __restrict__ Wv,
    float* __restrict__ part)
{
    const int j0 = blockIdx.x * 1024 + threadIdx.x * 4;   // 6 col-blocks of 1024
    const int i0 = blockIdx.y * (HID_ / SPLIT);           // 32-row chunk
    __shared__ float hs[HID_ / SPLIT];
    if (threadIdx.x < HID_ / SPLIT) hs[threadIdx.x] = hid[i0 + threadIdx.x];
    __syncthreads();

    const float* W; int ldw; int col;
    if (j0 < 4096)       { W = Wq; ldw = 4096; col = j0; }
    else if (j0 < 5120)  { W = Wk; ldw = 1024; col = j0 - 4096; }
    else                 { W = Wv; ldw = 1024; col = j0 - 5120; }

    float4 acc = {0.f, 0.f, 0.f, 0.f};
    const float* p = W + (size_t)i0 * ldw + col;
    #pragma unroll 8
    for (int i = 0; i < HID_ / SPLIT; ++i) {
        const float4 wv = *(const float4*)(p + (size_t)i * ldw);
        const float h = hs[i];
        acc.x += h * wv.x; acc.y += h * wv.y; acc.z += h * wv.z; acc.w += h * wv.w;
    }
    *(float4*)&part[(size_t)blockIdx.y * NQKV + j0] = acc;
}

// ---------------- kernel 2: reduce partials + RoPE ----------------
__global__ __launch_bounds__(256) void k_qkv_reduce(
    const float* __restrict__ part, const float* __restrict__ cosv,
    const float* __restrict__ sinv, float* __restrict__ qkv)
{
    const int j = blockIdx.x * 256 + threadIdx.x;  // 24 blocks
    float s = 0.f;
    #pragma unroll 8
    for (int k = 0; k < SPLIT; ++k) s += part[(size_t)k * NQKV + j];
    __shared__ float buf[256];
    buf[threadIdx.x] = s;
    __syncthreads();
    float out = s;
    if (j < 5120) {  // q and k get RoPE; v passes through
        const int d = j & 127;
        const float rot = (d < 64) ? -buf[threadIdx.x + 64] : buf[threadIdx.x - 64];
        out = s * cosv[d] + rot * sinv[d];
    }
    qkv[j] = out;
}

// ---------------- kernel 3: fused flash-decode attention ----------------
// block = 256 thr = 4 waves; wave g handles head (kh*4+g).
// K/V tiles (TB=16 tokens, 16 KB) in a 3-buffer LDS pipeline staged by
// async global_load_lds; counted s_waitcnt vmcnt(5) + raw s_barrier keep
// TWO stages in flight across barriers (never drain to 0 in the loop).
// Every wave stages its own scale copy so per-wave VMEM counts are uniform
// (5 ops/stage/wave). LDS XOR-swizzled (byte ^= (row&3)<<7) on both the
// staging SOURCE address and the read offset (verified R6, conflicts = 0).
// Fixed-base softmax: wgt = exp(s - 8)  (exact; base cancels in final ratio).
__global__ __launch_bounds__(256) void k_attn(
    const int* __restrict__ kqx, const float* __restrict__ kscale,
    const int* __restrict__ vqx, const float* __restrict__ vscale,
    const float* __restrict__ qkv, float* __restrict__ pv_c,
    float* __restrict__ l_c)
{
    const int kh = blockIdx.y;
    const int c0 = blockIdx.x * CHUNK;
    const int tid = threadIdx.x;
    const int g = tid >> 6;          // wave index = head-in-group (uniform/wave)
    const int l = tid & 63;
    const int t = l >> 3, j = l & 7;

    __shared__ int   kbuf[3][TB * 128];   // 8 KB per buf
    __shared__ int   vbuf[3][TB * 128];   // 8 KB per buf
    __shared__ float scbuf[3][4][64];     // per-wave copy: [0..15]=ksc, [16..31]=vsc

    float4 qf[4];
    #pragma unroll
    for (int k = 0; k < 4; ++k)
        qf[k] = *(const float4*)&qkv[(kh * 4 + g) * D_ + (j + 8 * k) * 4];

    float ls = 0.f;
    float4 acc[4];
    #pragma unroll
    for (int k = 0; k < 4; ++k) acc[k] = make_float4(0.f, 0.f, 0.f, 0.f);

    // ---- stage one tile into buf: wave g covers rows [g*4, g*4+4); 5 VMEM ops/wave ----
    auto stage = [&](int buf, int tok0) {
        #pragma unroll
        for (int i = 0; i < 2; ++i) {
            const int seg = g * 4 + i * 2;            // first of 2 rows in this 1KB instr
            const int row = seg + (l >> 5);           // per-lane row
            const int col = ((l & 31) * 16) ^ ((row & 3) << 7);  // inverse-swizzled source (bytes)
            const size_t goff = ((size_t)(tok0 + row) * HKV_ + kh) * D_ + (col >> 2);
            GLOAD_LDS16(kqx + goff, (char*)&kbuf[buf][0] + seg * 512);
            GLOAD_LDS16(vqx + goff, (char*)&vbuf[buf][0] + seg * 512);
        }
        {   // per-wave scale copy: 16 ksc + 16 vsc (+32 pad lanes)
            const float* gs;
            if (l < 16)      gs = kscale + (size_t)(tok0 + l) * HKV_ + kh;
            else if (l < 32) gs = vscale + (size_t)(tok0 + (l - 16)) * HKV_ + kh;
            else             gs = kscale + (size_t)tok0 * HKV_ + kh;  // pad lanes
            GLOAD_LDS4(gs, (char*)&scbuf[buf][g][0]);
        }
    };

    stage(0, c0);
    stage(1, c0 + TB);

    for (int tile = 0; tile < NT; ++tile) {
        // drain ONLY stage(tile): 5 ops of the younger stage stay in flight
        if (tile + 1 < NT) { WAITV(5); } else { WAITV(0); }
        __builtin_amdgcn_s_barrier();
        __builtin_amdgcn_sched_barrier(0);
        if (tile + 2 < NT) stage((tile + 2) % 3, c0 + (tile + 2) * TB);

        const int buf = tile % 3;
        #pragma unroll
        for (int it = 0; it < TB / 8; ++it) {
            const int row = it * 8 + t;
            const int sw = (row & 3) << 7;
            int4 kv[4], vv[4];
            #pragma unroll
            for (int k = 0; k < 4; ++k) {
                const int off = row * 512 + (((j + 8 * k) * 16) ^ sw);
                kv[k] = *(const int4*)((const char*)&kbuf[buf][0] + off);
                vv[k] = *(const int4*)((const char*)&vbuf[buf][0] + off);
            }
            const float sc = scbuf[buf][g][row] * SCALE_;
            const float vs = scbuf[buf][g][16 + row];

            float d0 = 0.f, d1 = 0.f, d2 = 0.f, d3 = 0.f;
            d0 += (float)kv[0].x * qf[0].x + (float)kv[0].y * qf[0].y +
                  (float)kv[0].z * qf[0].z + (float)kv[0].w * qf[0].w;
            d1 += (float)kv[1].x * qf[1].x + (float)kv[1].y * qf[1].y +
                  (float)kv[1].z * qf[1].z + (float)kv[1].w * qf[1].w;
            d2 += (float)kv[2].x * qf[2].x + (float)kv[2].y * qf[2].y +
                  (float)kv[2].z * qf[2].z + (float)kv[2].w * qf[2].w;
            d3 += (float)kv[3].x * qf[3].x + (float)kv[3].y * qf[3].y +
                  (float)kv[3].z * qf[3].z + (float)kv[3].w * qf[3].w;
            float dot = (d0 + d1) + (d2 + d3);
            dot += __shfl_xor(dot, 1, 64);
            dot += __shfl_xor(dot, 2, 64);
            dot += __shfl_xor(dot, 4, 64);

            const float wgt = __expf(dot * sc - BASE_);
            ls += wgt;
            const float wv = wgt * vs;
            #pragma unroll
            for (int k = 0; k < 4; ++k) {
                acc[k].x += wv * (float)vv[k].x;
                acc[k].y += wv * (float)vv[k].y;
                acc[k].z += wv * (float)vv[k].z;
                acc[k].w += wv * (float)vv[k].w;
            }
        }
        // no per-tile drain: next iteration's counted wait + barrier handles it
    }

    // sum across the 8 token slots (lane bits 3..5); j-lanes hold disjoint d
    #pragma unroll
    for (int msk = 8; msk < 64; msk <<= 1) {
        #pragma unroll
        for (int k = 0; k < 4; ++k) {
            acc[k].x += __shfl_xor(acc[k].x, msk, 64);
            acc[k].y += __shfl_xor(acc[k].y, msk, 64);
            acc[k].z += __shfl_xor(acc[k].z, msk, 64);
            acc[k].w += __shfl_xor(acc[k].w, msk, 64);
        }
        ls += __shfl_xor(ls, msk, 64);
    }
    if (t == 0) {
        float* dst = pv_c + ((size_t)(blockIdx.x * HKV_ + kh) * 4 + g) * D_;
        #pragma unroll
        for (int k = 0; k < 4; ++k) *(float4*)(dst + (j + 8 * k) * 4) = acc[k];
        if (j == 0) l_c[(blockIdx.x * HKV_ + kh) * 4 + g] = ls;
    }
}

// ---------------- kernel 4: combine (pure sums, fixed base) ----------------
// one block per head; 128 threads = d
__global__ __launch_bounds__(128) void k_combine(
    const float* __restrict__ pv_c, const float* __restrict__ l_c,
    const float* __restrict__ qkv, float* __restrict__ attn)
{
    const int h = blockIdx.x;        // 32 blocks
    const int d = threadIdx.x;       // 128
    const int kh = h >> 2, g = h & 3;

    __shared__ float sred[128];
    sred[d] = qkv[h * D_ + d] * qkv[4096 + kh * D_ + d];
    __syncthreads();
    for (int s2 = 64; s2 > 0; s2 >>= 1) {
        if (d < s2) sred[d] += sred[d + s2];
        __syncthreads();
    }
    const float pc = __expf(sred[0] * SCALE_ - BASE_);  // current-token weight

    float pv = 0.f, dsum = 0.f;
    for (int c = 0; c < NCHUNK; ++c) {
        pv   += pv_c[((size_t)(c * HKV_ + kh) * 4 + g) * D_ + d];
        dsum += l_c[(c * HKV_ + kh) * 4 + g];
    }
    const float vcur = qkv[5120 + kh * D_ + d];
    attn[h * D_ + d] = (pv + pc * vcur) / (dsum + pc);
}

// ---------------- kernel 5: output GEMV split-K partials ----------------
__global__ __launch_bounds__(256) void k_out_part(
    const float* __restrict__ attn, const float* __restrict__ Wo,
    float* __restrict__ opart)
{
    const int j0 = blockIdx.x * 1024 + threadIdx.x * 4;  // 4 col-blocks
    const int i0 = blockIdx.y * (HID_ / SPLIT);
    __shared__ float hs[HID_ / SPLIT];
    if (threadIdx.x < HID_ / SPLIT) hs[threadIdx.x] = attn[i0 + threadIdx.x];
    __syncthreads();
    float4 acc = {0.f, 0.f, 0.f, 0.f};
    const float* p = Wo + (size_t)i0 * HID_ + j0;
    #pragma unroll 8
    for (int i = 0; i < HID_ / SPLIT; ++i) {
        const float4 wv = *(const float4*)(p + (size_t)i * HID_);
        const float h = hs[i];
        acc.x += h * wv.x; acc.y += h * wv.y; acc.z += h * wv.z; acc.w += h * wv.w;
    }
    *(float4*)&opart[(size_t)blockIdx.y * HID_ + j0] = acc;
}

// ---------------- kernel 6: reduce output partials ----------------
__global__ __launch_bounds__(256) void k_out_reduce(
    const float* __restrict__ opart, float* __restrict__ out)
{
    const int j = blockIdx.x * 256 + threadIdx.x;  // 16 blocks
    float s = 0.f;
    #pragma unroll 8
    for (int k = 0; k < SPLIT; ++k) s += opart[(size_t)k * HID_ + j];
    out[j] = s;
}

extern "C" void kernel_launch(void* const* d_in, const int* in_sizes, int n_in,
                              void* d_out, int out_size, void* d_ws, size_t ws_size,
                              hipStream_t stream) {
    const float* hid    = (const float*)d_in[0];
    const int*   kqx    = (const int*)d_in[1];
    const float* kscale = (const float*)d_in[2];
    const int*   vqx    = (const int*)d_in[3];
    const float* vscale = (const float*)d_in[4];
    const float* cosv   = (const float*)d_in[5];
    const float* sinv   = (const float*)d_in[6];
    const float* Wq     = (const float*)d_in[7];
    const float* Wk     = (const float*)d_in[8];
    const float* Wv     = (const float*)d_in[9];
    const float* Wo     = (const float*)d_in[10];
    float* ws  = (float*)d_ws;
    float* out = (float*)d_out;

    k_qkv_part  <<<dim3(6, SPLIT), 256, 0, stream>>>(hid, Wq, Wk, Wv, ws + WS_QKV_PART);
    k_qkv_reduce<<<dim3(24),       256, 0, stream>>>(ws + WS_QKV_PART, cosv, sinv, ws + WS_QKV);
    k_attn      <<<dim3(NCHUNK, HKV_), 256, 0, stream>>>(kqx, kscale, vqx, vscale,
                                                         ws + WS_QKV, ws + WS_PV_C,
                                                         ws + WS_L_C);
    k_combine   <<<dim3(H_),       128, 0, stream>>>(ws + WS_PV_C, ws + WS_L_C,
                                                     ws + WS_QKV, ws + WS_ATTN);
    k_out_part  <<<dim3(4, SPLIT), 256, 0, stream>>>(ws + WS_ATTN, Wo, ws + WS_OPART);
    k_out_reduce<<<dim3(16),       256, 0, stream>>>(ws + WS_OPART, out);
}